// Round 1
// baseline (48.521 us; speedup 1.0000x reference)
//
#include <hip/hip_runtime.h>
#include <math.h>

#define BB 8
#define SS 2048
#define DD 64
#define GG 5
#define OSQ 512

// cos(2*pi*rev) via HW: v_cos_f32 takes revolutions, reduce with v_fract first.
__device__ __forceinline__ float cos_rev(float rev) {
    float fr, c;
    asm("v_fract_f32 %0, %1" : "=v"(fr) : "v"(rev));
    asm("v_cos_f32 %0, %1" : "=v"(c) : "v"(fr));
    return c;
}

// Kernel A: fused Z0 = seq@M^T, LayerNorm, W on-the-fly (registers), T, V = T + Z0.
// Grid: 256 blocks x 512 threads. Block handles k0 = blockIdx.x*8 .. +8, all 8 batches.
__global__ __launch_bounds__(512) void kA(const float* __restrict__ seq,
                                          const float* __restrict__ M,
                                          const float* __restrict__ P,
                                          const float* __restrict__ gamma,
                                          const float* __restrict__ beta,
                                          float* __restrict__ Vg) {
    __shared__ float SZ[64][68];    // seq rows (phase1), then Z rows (union)
    __shared__ float Mt[64][64];    // M transposed: Mt[d][o]
    __shared__ float Z0l[64][68];   // pre-LN projection rows
    __shared__ float Vl[4][8][66];  // staging for coalesced V writes

    const int t = threadIdx.x;
    const int l = t & 63;
    const int w = t >> 6;          // wave index == batch for the flush phase
    const int k0 = blockIdx.x * 8;
    const int rI = t >> 3;         // 0..63: row index (phase1) / W-row i (phase2)
    const int oc = t & 7;          // 8-wide column slice / selected batch

    // ---- P slice (8 (i,j) pairs x 5 g) and reciprocal periods into registers ----
    float pr[40], inv[40];
    {
        const float4* P4 = (const float4*)(P + t * 40);
        #pragma unroll
        for (int q = 0; q < 10; ++q) {
            float4 v = P4[q];
            pr[q*4+0] = v.x; pr[q*4+1] = v.y; pr[q*4+2] = v.z; pr[q*4+3] = v.w;
        }
        #pragma unroll
        for (int m = 0; m < 8; ++m)
            #pragma unroll
            for (int g = 0; g < GG; ++g)
                inv[m*5+g] = 1.0f / (float)(5*(8*t + m) + g + 2);
    }

    // ---- stage seq rows (64 rows: r = b*8+kc) and transposed M ----
    #pragma unroll
    for (int q = 0; q < 2; ++q) {
        int v = q*512 + t;                 // 0..1023 float4s
        int rr = v >> 4, cc = v & 15;
        int bb = rr >> 3, kq = rr & 7;
        float4 sv = *(const float4*)&seq[((size_t)bb*SS + k0 + kq)*DD + cc*4];
        *(float4*)&SZ[rr][cc*4] = sv;
    }
    #pragma unroll
    for (int q = 0; q < 2; ++q) {
        int v = q*512 + t;
        int oo = v >> 4, cc = v & 15;
        float4 mv = *(const float4*)&M[oo*DD + cc*4];
        Mt[cc*4+0][oo] = mv.x;
        Mt[cc*4+1][oo] = mv.y;
        Mt[cc*4+2][oo] = mv.z;
        Mt[cc*4+3][oo] = mv.w;
    }
    float gm[8], bt[8];
    {
        const float4* g4 = (const float4*)&gamma[oc*8];
        const float4* b4 = (const float4*)&beta[oc*8];
        float4 a = g4[0], b = g4[1], c = b4[0], d = b4[1];
        gm[0]=a.x; gm[1]=a.y; gm[2]=a.z; gm[3]=a.w;
        gm[4]=b.x; gm[5]=b.y; gm[6]=b.z; gm[7]=b.w;
        bt[0]=c.x; bt[1]=c.y; bt[2]=c.z; bt[3]=c.w;
        bt[4]=d.x; bt[5]=d.y; bt[6]=d.z; bt[7]=d.w;
    }
    __syncthreads();

    // ---- phase 1: Z0[r][o] for our 64 rows; thread owns (rI, 8 o's) ----
    float z0[8] = {0,0,0,0,0,0,0,0};
    #pragma unroll 4
    for (int d4 = 0; d4 < 16; ++d4) {
        float4 sv = *(const float4*)&SZ[rI][d4*4];
        float sarr[4] = {sv.x, sv.y, sv.z, sv.w};
        #pragma unroll
        for (int dd = 0; dd < 4; ++dd) {
            float sd = sarr[dd];
            float4 ma = *(const float4*)&Mt[d4*4+dd][oc*8];
            float4 mb = *(const float4*)&Mt[d4*4+dd][oc*8+4];
            z0[0] = fmaf(sd, ma.x, z0[0]);
            z0[1] = fmaf(sd, ma.y, z0[1]);
            z0[2] = fmaf(sd, ma.z, z0[2]);
            z0[3] = fmaf(sd, ma.w, z0[3]);
            z0[4] = fmaf(sd, mb.x, z0[4]);
            z0[5] = fmaf(sd, mb.y, z0[5]);
            z0[6] = fmaf(sd, mb.z, z0[6]);
            z0[7] = fmaf(sd, mb.w, z0[7]);
        }
    }
    // LayerNorm stats across the 8-lane group (row = 64 elements)
    float s1 = ((z0[0]+z0[1])+(z0[2]+z0[3])) + ((z0[4]+z0[5])+(z0[6]+z0[7]));
    s1 += __shfl_xor(s1, 1); s1 += __shfl_xor(s1, 2); s1 += __shfl_xor(s1, 4);
    float mu = s1 * 0.015625f;
    float sq = 0.f;
    #pragma unroll
    for (int m = 0; m < 8; ++m) { float dv = z0[m] - mu; sq = fmaf(dv, dv, sq); }
    sq += __shfl_xor(sq, 1); sq += __shfl_xor(sq, 2); sq += __shfl_xor(sq, 4);
    float rstd = rsqrtf(sq * 0.015625f + 1e-5f);

    // save Z0 rows
    *(float4*)&Z0l[rI][oc*8]   = make_float4(z0[0], z0[1], z0[2], z0[3]);
    *(float4*)&Z0l[rI][oc*8+4] = make_float4(z0[4], z0[5], z0[6], z0[7]);
    __syncthreads();   // everyone done reading SZ(seq) before Z overwrite
    {
        float zn[8];
        #pragma unroll
        for (int m = 0; m < 8; ++m) zn[m] = fmaf((z0[m] - mu) * rstd, gm[m], bt[m]);
        *(float4*)&SZ[rI][oc*8]   = make_float4(zn[0], zn[1], zn[2], zn[3]);
        *(float4*)&SZ[rI][oc*8+4] = make_float4(zn[4], zn[5], zn[6], zn[7]);
    }
    __syncthreads();

    // ---- phase 2: per k: W (regs) -> T partials -> butterfly -> V ----
    #pragma unroll 1
    for (int kc = 0; kc < 8; ++kc) {
        const float kf = (float)(k0 + kc);
        float wv[8];
        #pragma unroll
        for (int m = 0; m < 8; ++m) {
            float acc = 0.f;
            #pragma unroll
            for (int g = 0; g < GG; ++g)
                acc = fmaf(pr[m*5+g], cos_rev(kf * inv[m*5+g]), acc);
            wv[m] = acc;
        }
        float part[8];
        #pragma unroll
        for (int b = 0; b < 8; ++b) {
            const float* zr = &SZ[b*8 + kc][oc*8];
            float4 za = *(const float4*)zr;
            float4 zb = *(const float4*)(zr + 4);
            float s = za.x * wv[0];
            s = fmaf(za.y, wv[1], s); s = fmaf(za.z, wv[2], s); s = fmaf(za.w, wv[3], s);
            s = fmaf(zb.x, wv[4], s); s = fmaf(zb.y, wv[5], s);
            s = fmaf(zb.z, wv[6], s); s = fmaf(zb.w, wv[7], s);
            part[b] = s;
        }
        #pragma unroll
        for (int b = 0; b < 8; ++b) {
            part[b] += __shfl_xor(part[b], 1);
            part[b] += __shfl_xor(part[b], 2);
            part[b] += __shfl_xor(part[b], 4);
        }
        // select part[oc] with a static cndmask tree (no dynamic reg indexing)
        float a0 = (oc & 1) ? part[1] : part[0];
        float a2 = (oc & 1) ? part[3] : part[2];
        float a4 = (oc & 1) ? part[5] : part[4];
        float a6 = (oc & 1) ? part[7] : part[6];
        float b0 = (oc & 2) ? a2 : a0;
        float b4 = (oc & 2) ? a6 : a4;
        float val = (oc & 4) ? b4 : b0;
        val += Z0l[oc*8 + kc][rI];        // V = T + Z0
        Vl[kc & 3][oc][rI] = val;

        if ((kc & 3) == 3) {
            __syncthreads();
            const int kb = kc - 3;
            #pragma unroll
            for (int q = 0; q < 4; ++q)
                Vg[((size_t)w*SS + k0 + kb + q)*DD + l] = Vl[q][w][l];
            __syncthreads();
        }
    }
}

// Kernel B: out_partial[kc][b][o][i] = sum_{k in chunk} V[b,k,i] * Linker[k,o]
// Grid: 512 blocks (b x otile x kc=8) x 256 threads, 4x4 register tile.
__global__ __launch_bounds__(256) void kB(const float* __restrict__ V,
                                          const float* __restrict__ Lnk,
                                          float* __restrict__ part) {
    __shared__ float Ls[16][64];
    __shared__ float Vs[16][64];
    const int t = threadIdx.x;
    const int bid = blockIdx.x;
    const int kc = bid & 7;
    const int ot = (bid >> 3) & 7;
    const int b  = bid >> 6;
    const int o0 = ot * 64;
    const int kbase = kc * 256;
    const int oq = t >> 4, iq = t & 15;
    float acc[4][4];
    #pragma unroll
    for (int i = 0; i < 4; ++i)
        #pragma unroll
        for (int j = 0; j < 4; ++j) acc[i][j] = 0.f;

    for (int ch = 0; ch < 16; ++ch) {
        const int ks = kbase + ch*16;
        __syncthreads();
        if (t < 128) {
            #pragma unroll
            for (int q = 0; q < 2; ++q) {
                int v = q*128 + t;
                int kk = v >> 4, cc = v & 15;
                *(float4*)&Ls[kk][cc*4] = *(const float4*)&Lnk[(size_t)(ks+kk)*OSQ + o0 + cc*4];
            }
        } else {
            const int tt = t - 128;
            const float4* src = (const float4*)&V[((size_t)b*SS + ks)*DD];
            #pragma unroll
            for (int q = 0; q < 2; ++q) {
                int v = q*128 + tt;
                ((float4*)Vs)[v] = src[v];
            }
        }
        __syncthreads();
        #pragma unroll
        for (int kk = 0; kk < 16; ++kk) {
            float4 lo = *(const float4*)&Ls[kk][oq*4];
            float4 vi = *(const float4*)&Vs[kk][iq*4];
            acc[0][0] = fmaf(lo.x, vi.x, acc[0][0]);
            acc[0][1] = fmaf(lo.x, vi.y, acc[0][1]);
            acc[0][2] = fmaf(lo.x, vi.z, acc[0][2]);
            acc[0][3] = fmaf(lo.x, vi.w, acc[0][3]);
            acc[1][0] = fmaf(lo.y, vi.x, acc[1][0]);
            acc[1][1] = fmaf(lo.y, vi.y, acc[1][1]);
            acc[1][2] = fmaf(lo.y, vi.z, acc[1][2]);
            acc[1][3] = fmaf(lo.y, vi.w, acc[1][3]);
            acc[2][0] = fmaf(lo.z, vi.x, acc[2][0]);
            acc[2][1] = fmaf(lo.z, vi.y, acc[2][1]);
            acc[2][2] = fmaf(lo.z, vi.z, acc[2][2]);
            acc[2][3] = fmaf(lo.z, vi.w, acc[2][3]);
            acc[3][0] = fmaf(lo.w, vi.x, acc[3][0]);
            acc[3][1] = fmaf(lo.w, vi.y, acc[3][1]);
            acc[3][2] = fmaf(lo.w, vi.z, acc[3][2]);
            acc[3][3] = fmaf(lo.w, vi.w, acc[3][3]);
        }
    }
    float* dst = part + (size_t)kc * (BB*OSQ*DD);
    #pragma unroll
    for (int oo = 0; oo < 4; ++oo) {
        int o = o0 + oq*4 + oo;
        *(float4*)&dst[((size_t)b*OSQ + o)*DD + iq*4] =
            make_float4(acc[oo][0], acc[oo][1], acc[oo][2], acc[oo][3]);
    }
}

// Kernel C: reduce 8 partials into d_out.
__global__ __launch_bounds__(256) void kC(const float* __restrict__ part,
                                          float* __restrict__ out) {
    const int x = blockIdx.x * 256 + threadIdx.x;   // float4 index, 65536 total
    const float4* p4 = (const float4*)part;
    float4 s = p4[x];
    #pragma unroll
    for (int p = 1; p < 8; ++p) {
        float4 a = p4[x + p*65536];
        s.x += a.x; s.y += a.y; s.z += a.z; s.w += a.w;
    }
    ((float4*)out)[x] = s;
}

extern "C" void kernel_launch(void* const* d_in, const int* in_sizes, int n_in,
                              void* d_out, int out_size, void* d_ws, size_t ws_size,
                              hipStream_t stream) {
    const float* seq   = (const float*)d_in[0];
    const float* M     = (const float*)d_in[1];
    const float* P     = (const float*)d_in[2];
    const float* Lnk   = (const float*)d_in[3];
    const float* gamma = (const float*)d_in[4];
    const float* beta  = (const float*)d_in[5];

    float* V    = (float*)d_ws;                       // B*S*D   = 1048576 f32 (4 MB)
    float* part = V + (size_t)BB*SS*DD;               // 8*B*OSQ*D = 2097152 f32 (8 MB)

    kA<<<256, 512, 0, stream>>>(seq, M, P, gamma, beta, V);
    kB<<<512, 256, 0, stream>>>(V, Lnk, part);
    kC<<<256, 256, 0, stream>>>(part, (float*)d_out);
}

// Round 2
// 31.396 us; speedup vs baseline: 1.5454x; 1.5454x over previous
//
#include <hip/hip_runtime.h>
#include <math.h>

#define BB 8
#define SS 2048
#define DDIM 64
#define GG 5
#define OSQ 512

typedef unsigned short u16;
typedef unsigned int u32;
typedef __attribute__((ext_vector_type(8))) short s16x8;
typedef __attribute__((ext_vector_type(4))) float v4f;
typedef __attribute__((ext_vector_type(16))) float v16f;

__device__ __forceinline__ float rcp_f(float x) {
    float r; asm("v_rcp_f32 %0, %1" : "=v"(r) : "v"(x)); return r;
}
// cos(2*pi*x) for arbitrary x (revolutions): fract then HW cos
__device__ __forceinline__ float cos_rev(float x) {
    float fr, c;
    asm("v_fract_f32 %0, %1" : "=v"(fr) : "v"(x));
    asm("v_cos_f32 %0, %1" : "=v"(c) : "v"(fr));
    return c;
}
// cos(2*pi*x) for x already in [0,1)
__device__ __forceinline__ float cos01(float x) {
    float c; asm("v_cos_f32 %0, %1" : "=v"(c) : "v"(x)); return c;
}
__device__ __forceinline__ u16 f2bf(float f) {
    u32 u = __float_as_uint(f);
    return (u16)((u + 0x7FFFu + ((u >> 16) & 1u)) >> 16);
}
__device__ __forceinline__ void gload16(const void* g, void* l) {
    __builtin_amdgcn_global_load_lds((const __attribute__((address_space(1))) void*)g,
                                     (__attribute__((address_space(3))) void*)l, 16, 0, 0);
}

// ---------------------------------------------------------------------------
// kT: Lt_swz[o][k] bf16 = Linker[k][o], 16B-slots XOR-swizzled by (o&7) within
// each 128-k segment (so kB's linear global_load_lds + swizzled ds_read works).
// ---------------------------------------------------------------------------
__global__ __launch_bounds__(256) void kT(const float* __restrict__ Lnk,
                                          u16* __restrict__ Lt) {
    __shared__ float lt[128][68];
    const int t = threadIdx.x;
    const int k0 = (blockIdx.x & 15) * 128;
    const int o0 = (blockIdx.x >> 4) * 64;
    {
        int kk = t >> 1, hf = t & 1;
        const float4* src = (const float4*)&Lnk[(size_t)(k0 + kk) * OSQ + o0 + hf * 32];
        #pragma unroll
        for (int q = 0; q < 8; ++q) {
            float4 v = src[q];
            *(float4*)&lt[kk][hf * 32 + q * 4] = v;
        }
    }
    __syncthreads();
    #pragma unroll
    for (int q = 0; q < 4; ++q) {
        int idx = q * 256 + t;
        int o = idx >> 4, s = idx & 15;
        u32 w0 = 0, w1 = 0, w2 = 0, w3 = 0;
        w0 = (u32)f2bf(lt[s * 8 + 0][o]) | ((u32)f2bf(lt[s * 8 + 1][o]) << 16);
        w1 = (u32)f2bf(lt[s * 8 + 2][o]) | ((u32)f2bf(lt[s * 8 + 3][o]) << 16);
        w2 = (u32)f2bf(lt[s * 8 + 4][o]) | ((u32)f2bf(lt[s * 8 + 5][o]) << 16);
        w3 = (u32)f2bf(lt[s * 8 + 6][o]) | ((u32)f2bf(lt[s * 8 + 7][o]) << 16);
        int og = o0 + o;
        uint4 pk; pk.x = w0; pk.y = w1; pk.z = w2; pk.w = w3;
        *(uint4*)&Lt[(size_t)og * SS + k0 + ((s ^ (og & 7)) * 8)] = pk;
    }
}

// ---------------------------------------------------------------------------
// kA: fused  Z0 = seq@M^T (MFMA bf16), LayerNorm, W on-the-fly (cos recurrence),
// T = Z@W^T per-k (MFMA bf16), V = T + Z0 written directly as swizzled
// k-major Vt[b][i][k] bf16.
// Grid 256 x 512.  Block owns k0..k0+7, all 8 batches.
// ---------------------------------------------------------------------------
__global__ __launch_bounds__(512, 2) void kA(const float* __restrict__ seq,
                                             const float* __restrict__ Mm,
                                             const float* __restrict__ P,
                                             const float* __restrict__ gamma,
                                             const float* __restrict__ beta,
                                             u16* __restrict__ Vt) {
    __shared__ __align__(16) u16 SEQb[64 * 64];   // bf16, swizzled by (row&7)
    __shared__ __align__(16) u16 Mb[64 * 64];     // bf16, swizzled by (o&7)
    __shared__ __align__(16) u16 SZb[64 * 64];    // Z bf16, swizzled by (row>>3)&7 = b
    __shared__ float Z0l[64 * 68];                // pre-LN projection, f32
    __shared__ float Ta[2 * 64 * 10];             // T j-half partials [h][i][b(pad10)]

    const int t = threadIdx.x;
    const int l = t & 63;
    const int w = t >> 6;
    const int k0 = blockIdx.x * 8;
    const float kf0 = (float)k0;

    // W-fragment ownership (matches mfma_16x16x32 B-layout): n=i, k-chunk
    const int h = w >> 2;                 // j-half (0: j 0..31, 1: j 32..63)
    const int i0 = (w & 3) * 16;
    const int i_w = i0 + (l & 15);
    const int jc_w = h * 4 + (l >> 4);    // 8-j chunk index 0..7

    // ---- P coefficients (40 contiguous f32) ----
    float pr[40];
    {
        const float4* P4 = (const float4*)(P + ((size_t)i_w * 64 + jc_w * 8) * 5);
        #pragma unroll
        for (int q = 0; q < 10; ++q) {
            float4 v = P4[q];
            pr[q * 4 + 0] = v.x; pr[q * 4 + 1] = v.y; pr[q * 4 + 2] = v.z; pr[q * 4 + 3] = v.w;
        }
    }

    // ---- stage seq, M as bf16 (swizzled) ----
    {
        int row = t >> 3, ch = t & 7;
        int b = row >> 3, kq = row & 7;
        const float* sp = &seq[((size_t)b * SS + k0 + kq) * DDIM + ch * 8];
        float4 a = *(const float4*)sp, bb4 = *(const float4*)(sp + 4);
        uint4 pk;
        pk.x = (u32)f2bf(a.x) | ((u32)f2bf(a.y) << 16);
        pk.y = (u32)f2bf(a.z) | ((u32)f2bf(a.w) << 16);
        pk.z = (u32)f2bf(bb4.x) | ((u32)f2bf(bb4.y) << 16);
        pk.w = (u32)f2bf(bb4.z) | ((u32)f2bf(bb4.w) << 16);
        *(uint4*)&SEQb[row * 64 + ((ch ^ (row & 7)) * 8)] = pk;

        const float* mp = &Mm[(size_t)row * DDIM + ch * 8];
        float4 c = *(const float4*)mp, d = *(const float4*)(mp + 4);
        uint4 pm;
        pm.x = (u32)f2bf(c.x) | ((u32)f2bf(c.y) << 16);
        pm.y = (u32)f2bf(c.z) | ((u32)f2bf(c.w) << 16);
        pm.z = (u32)f2bf(d.x) | ((u32)f2bf(d.y) << 16);
        pm.w = (u32)f2bf(d.z) | ((u32)f2bf(d.w) << 16);
        *(uint4*)&Mb[row * 64 + ((ch ^ (row & 7)) * 8)] = pm;
    }

    // ---- cosine recurrence init (trans pipe; overlaps staging) ----
    // period p = (i*64+j)*5 + g + 2 ; theta = 1/p rev
    float c0[40], c1[40], t2c[40];
    #pragma unroll
    for (int m = 0; m < 8; ++m) {
        #pragma unroll
        for (int g = 0; g < GG; ++g) {
            int idx = m * 5 + g;
            float pf = (float)((i_w * 64 + jc_w * 8 + m) * 5 + g + 2);
            float inv = rcp_f(pf);
            c0[idx] = cos_rev(kf0 * inv);
            c1[idx] = cos_rev((kf0 + 1.0f) * inv);
            float ct = cos01(inv);
            t2c[idx] = ct + ct;
        }
    }

    // gamma/beta for LN (thread role: rI=t>>3, oc=t&7)
    float gm[8], bt[8];
    {
        int oc = t & 7;
        float4 a = *(const float4*)&gamma[oc * 8], b = *(const float4*)&gamma[oc * 8 + 4];
        float4 c = *(const float4*)&beta[oc * 8],  d = *(const float4*)&beta[oc * 8 + 4];
        gm[0]=a.x; gm[1]=a.y; gm[2]=a.z; gm[3]=a.w; gm[4]=b.x; gm[5]=b.y; gm[6]=b.z; gm[7]=b.w;
        bt[0]=c.x; bt[1]=c.y; bt[2]=c.z; bt[3]=c.w; bt[4]=d.x; bt[5]=d.y; bt[6]=d.z; bt[7]=d.w;
    }
    __syncthreads();

    // ---- phase 1: Z0 = seq @ M^T via mfma_32x32x16, waves 0-3 = quadrants ----
    if (w < 4) {
        const int qr = w & 1, qc = w >> 1;
        v16f acc = {0,0,0,0,0,0,0,0,0,0,0,0,0,0,0,0};
        const int rowA = qr * 32 + (l & 31);
        const int rowB = qc * 32 + (l & 31);
        #pragma unroll
        for (int ks = 0; ks < 4; ++ks) {
            int cA = (ks * 2 + (l >> 5)) ^ (rowA & 7);
            int cB = (ks * 2 + (l >> 5)) ^ (rowB & 7);
            s16x8 af = *(const s16x8*)&SEQb[rowA * 64 + cA * 8];
            s16x8 bf = *(const s16x8*)&Mb[rowB * 64 + cB * 8];
            acc = __builtin_amdgcn_mfma_f32_32x32x16_bf16(af, bf, acc, 0, 0, 0);
        }
        #pragma unroll
        for (int q = 0; q < 16; ++q) {
            int row = qr * 32 + (q & 3) + 8 * (q >> 2) + 4 * (l >> 5);
            int col = qc * 32 + (l & 31);
            Z0l[row * 68 + col] = acc[q];
        }
    }
    __syncthreads();

    // ---- LayerNorm (rows of 64, 8 threads/row) -> SZb bf16 (b-swizzled) ----
    {
        const int rI = t >> 3, oc = t & 7;
        float z0v[8];
        float4 a = *(const float4*)&Z0l[rI * 68 + oc * 8];
        float4 b = *(const float4*)&Z0l[rI * 68 + oc * 8 + 4];
        z0v[0]=a.x; z0v[1]=a.y; z0v[2]=a.z; z0v[3]=a.w; z0v[4]=b.x; z0v[5]=b.y; z0v[6]=b.z; z0v[7]=b.w;
        float s1 = ((z0v[0]+z0v[1])+(z0v[2]+z0v[3])) + ((z0v[4]+z0v[5])+(z0v[6]+z0v[7]));
        s1 += __shfl_xor(s1, 1); s1 += __shfl_xor(s1, 2); s1 += __shfl_xor(s1, 4);
        float mu = s1 * 0.015625f;
        float sq = 0.f;
        #pragma unroll
        for (int m = 0; m < 8; ++m) { float dv = z0v[m] - mu; sq = fmaf(dv, dv, sq); }
        sq += __shfl_xor(sq, 1); sq += __shfl_xor(sq, 2); sq += __shfl_xor(sq, 4);
        float rstd = rsqrtf(sq * 0.015625f + 1e-5f);
        u16 zb[8];
        #pragma unroll
        for (int m = 0; m < 8; ++m)
            zb[m] = f2bf(fmaf((z0v[m] - mu) * rstd, gm[m], bt[m]));
        uint4 pk;
        pk.x = (u32)zb[0] | ((u32)zb[1] << 16);
        pk.y = (u32)zb[2] | ((u32)zb[3] << 16);
        pk.z = (u32)zb[4] | ((u32)zb[5] << 16);
        pk.w = (u32)zb[6] | ((u32)zb[7] << 16);
        int slot = oc ^ ((rI >> 3) & 7);
        *(uint4*)&SZb[rI * 64 + slot * 8] = pk;
    }
    __syncthreads();

    // ---- phase 2: per k, W via recurrence -> T via mfma_16x16x32 -> V ----
    float vk[8];
    const int bcl = l & 7;                 // clamped A-row batch (lanes 8-15 dup)
    #pragma unroll
    for (int kc = 0; kc < 8; ++kc) {
        if (kc >= 2) {
            #pragma unroll
            for (int x = 0; x < 40; ++x) {
                float cn = fmaf(t2c[x], c1[x], -c0[x]);
                c0[x] = c1[x]; c1[x] = cn;
            }
        }
        s16x8 bw;
        #pragma unroll
        for (int j = 0; j < 8; ++j) {
            float a = 0.f;
            #pragma unroll
            for (int g = 0; g < GG; ++g) {
                float ph = (kc == 0) ? c0[j * 5 + g] : c1[j * 5 + g];
                a = fmaf(pr[j * 5 + g], ph, a);
            }
            bw[j] = (short)f2bf(a);
        }
        // A-frag: Z[b][j-window]  (rows = b, k = j)
        int arow = bcl * 8 + kc;
        int slot = (h * 4 + (l >> 4)) ^ bcl;
        s16x8 az = *(const s16x8*)&SZb[arow * 64 + slot * 8];
        v4f zc = {0.f, 0.f, 0.f, 0.f};
        v4f d = __builtin_amdgcn_mfma_f32_16x16x32_bf16(az, bw, zc, 0, 0, 0);
        // D: col(lane&15)=i, row((lane>>4)*4+reg)=b ; only lanes<32 hold b<8
        if (l < 32) {
            int ii = i0 + (l & 15);
            int bb = (l >> 4) * 4;
            #pragma unroll
            for (int r = 0; r < 4; ++r)
                Ta[h * 640 + ii * 10 + bb + r] = d[r];
        }
        __syncthreads();
        // assembly: thread (b=w, i=l): V = T(h0)+T(h1)+Z0
        vk[kc] = Ta[l * 10 + w] + Ta[640 + l * 10 + w] + Z0l[(w * 8 + kc) * 68 + l];
        __syncthreads();
    }
    // write Vt[b][i][k0..k0+7] bf16, slot-swizzled by (i&7) within 128-k segment
    {
        uint4 pk;
        pk.x = (u32)f2bf(vk[0]) | ((u32)f2bf(vk[1]) << 16);
        pk.y = (u32)f2bf(vk[2]) | ((u32)f2bf(vk[3]) << 16);
        pk.z = (u32)f2bf(vk[4]) | ((u32)f2bf(vk[5]) << 16);
        pk.w = (u32)f2bf(vk[6]) | ((u32)f2bf(vk[7]) << 16);
        int seg = k0 & ~127;
        int s0 = (k0 >> 3) & 15;
        size_t addr = ((size_t)(w * 64 + l)) * SS + seg + ((s0 ^ (l & 7)) * 8);
        *(uint4*)&Vt[addr] = pk;
    }
}

// ---------------------------------------------------------------------------
// kB: part[kw][b][o][i] += Lt^T-GEMM via mfma_32x32x16 bf16.
// Block: 64o x 64i tile, K-chunk 512 (kw), 4 waves split K, pairwise reduce.
// ---------------------------------------------------------------------------
__global__ __launch_bounds__(256) void kB(const u16* __restrict__ Lt,
                                          const u16* __restrict__ Vt,
                                          float* __restrict__ part) {
    __shared__ __align__(16) u16 TILES[32768];  // 64KB: Lt chunk [64][256] | Vt chunk
    const int t = threadIdx.x;
    const int l = t & 63, w = t >> 6;
    const int bid = blockIdx.x;
    const int kw = bid & 3, ot = (bid >> 2) & 7, b = bid >> 5;
    const int o0 = ot * 64;

    v16f acc0 = {0,0,0,0,0,0,0,0,0,0,0,0,0,0,0,0};
    v16f acc1 = acc0, acc2 = acc0, acc3 = acc0;

    #pragma unroll 1
    for (int ch = 0; ch < 2; ++ch) {
        const int kbase = kw * 512 + ch * 256;
        if (ch) __syncthreads();
        #pragma unroll
        for (int q = 0; q < 8; ++q) {
            int e16 = (w * 8 + q) * 64 + l;
            int row = e16 >> 5, cnk = e16 & 31;
            gload16(&Lt[(size_t)(o0 + row) * SS + kbase + cnk * 8], &TILES[(w * 8 + q) * 512]);
            gload16(&Vt[((size_t)b * 64 + row) * SS + kbase + cnk * 8], &TILES[16384 + (w * 8 + q) * 512]);
        }
        asm volatile("s_waitcnt vmcnt(0)" ::: "memory");
        __syncthreads();
        // wave w handles local k-window [w*64, w*64+64)
        #pragma unroll
        for (int ks = 0; ks < 4; ++ks) {
            int c2 = (w & 1) * 8 + ks * 2 + (l >> 5);   // slot within 128k-seg
            int seg = w >> 1;
            int r0 = l & 31, r1 = 32 + (l & 31);
            s16x8 a0 = *(const s16x8*)&TILES[r0 * 256 + seg * 128 + ((c2 ^ (r0 & 7)) * 8)];
            s16x8 a1 = *(const s16x8*)&TILES[r1 * 256 + seg * 128 + ((c2 ^ (r1 & 7)) * 8)];
            s16x8 b0 = *(const s16x8*)&TILES[16384 + r0 * 256 + seg * 128 + ((c2 ^ (r0 & 7)) * 8)];
            s16x8 b1 = *(const s16x8*)&TILES[16384 + r1 * 256 + seg * 128 + ((c2 ^ (r1 & 7)) * 8)];
            acc0 = __builtin_amdgcn_mfma_f32_32x32x16_bf16(a0, b0, acc0, 0, 0, 0);
            acc1 = __builtin_amdgcn_mfma_f32_32x32x16_bf16(a0, b1, acc1, 0, 0, 0);
            acc2 = __builtin_amdgcn_mfma_f32_32x32x16_bf16(a1, b0, acc2, 0, 0, 0);
            acc3 = __builtin_amdgcn_mfma_f32_32x32x16_bf16(a1, b1, acc3, 0, 0, 0);
        }
    }
    // cross-wave K reduction (pairwise), reuse TILES as f32 scratch
    __syncthreads();
    float* red = (float*)TILES;
    const int RS = 66;
    if (w >= 2) {
        int base = ((w - 2) * 64 + l) * RS;
        #pragma unroll
        for (int r = 0; r < 16; ++r) {
            red[base + r] = acc0[r]; red[base + 16 + r] = acc1[r];
            red[base + 32 + r] = acc2[r]; red[base + 48 + r] = acc3[r];
        }
    }
    __syncthreads();
    if (w < 2) {
        int base = (w * 64 + l) * RS;
        #pragma unroll
        for (int r = 0; r < 16; ++r) {
            acc0[r] += red[base + r]; acc1[r] += red[base + 16 + r];
            acc2[r] += red[base + 32 + r]; acc3[r] += red[base + 48 + r];
        }
    }
    __syncthreads();
    if (w == 1) {
        int base = l * RS;
        #pragma unroll
        for (int r = 0; r < 16; ++r) {
            red[base + r] = acc0[r]; red[base + 16 + r] = acc1[r];
            red[base + 32 + r] = acc2[r]; red[base + 48 + r] = acc3[r];
        }
    }
    __syncthreads();
    if (w == 0) {
        int base = l * RS;
        #pragma unroll
        for (int r = 0; r < 16; ++r) {
            acc0[r] += red[base + r]; acc1[r] += red[base + 16 + r];
            acc2[r] += red[base + 32 + r]; acc3[r] += red[base + 48 + r];
        }
        float* dst = part + (((size_t)kw * 8 + b) * OSQ) * 64;
        #pragma unroll
        for (int r = 0; r < 16; ++r) {
            int orow = (r & 3) + 8 * (r >> 2) + 4 * (l >> 5);
            int icol = l & 31;
            dst[(size_t)(o0 + orow) * 64 + icol]            = acc0[r];
            dst[(size_t)(o0 + orow) * 64 + 32 + icol]       = acc1[r];
            dst[(size_t)(o0 + 32 + orow) * 64 + icol]       = acc2[r];
            dst[(size_t)(o0 + 32 + orow) * 64 + 32 + icol]  = acc3[r];
        }
    }
}

// ---------------------------------------------------------------------------
// kC: out = sum of 4 K-split partials
// ---------------------------------------------------------------------------
__global__ __launch_bounds__(256) void kC(const float* __restrict__ part,
                                          float* __restrict__ out) {
    const int x = blockIdx.x * 256 + threadIdx.x;   // float4 index, 65536 total
    const float4* p4 = (const float4*)part;
    float4 s = p4[x];
    #pragma unroll
    for (int p = 1; p < 4; ++p) {
        float4 a = p4[x + p * 65536];
        s.x += a.x; s.y += a.y; s.z += a.z; s.w += a.w;
    }
    ((float4*)out)[x] = s;
}

extern "C" void kernel_launch(void* const* d_in, const int* in_sizes, int n_in,
                              void* d_out, int out_size, void* d_ws, size_t ws_size,
                              hipStream_t stream) {
    const float* seq   = (const float*)d_in[0];
    const float* Mm    = (const float*)d_in[1];
    const float* P     = (const float*)d_in[2];
    const float* Lnk   = (const float*)d_in[3];
    const float* gamma = (const float*)d_in[4];
    const float* beta  = (const float*)d_in[5];

    u16* Lt    = (u16*)d_ws;                              // 512*2048 bf16 = 2MB
    u16* Vt    = (u16*)((char*)d_ws + (2u << 20));        // 8*64*2048 bf16 = 2MB
    float* prt = (float*)((char*)d_ws + (4u << 20));      // 4*8*512*64 f32 = 4MB

    kT<<<128, 256, 0, stream>>>(Lnk, Lt);
    kA<<<256, 512, 0, stream>>>(seq, Mm, P, gamma, beta, Vt);
    kB<<<256, 256, 0, stream>>>(Lt, Vt, prt);
    kC<<<256, 256, 0, stream>>>(prt, (float*)d_out);
}

// Round 3
// 27.574 us; speedup vs baseline: 1.7596x; 1.1386x over previous
//
#include <hip/hip_runtime.h>
#include <math.h>

#define BB 8
#define SS 2048
#define DDIM 64
#define GG 5
#define OSQ 512

typedef unsigned short u16;
typedef unsigned int u32;
typedef __attribute__((ext_vector_type(8))) short s16x8;
typedef __attribute__((ext_vector_type(4))) float v4f;
typedef __attribute__((ext_vector_type(16))) float v16f;

__device__ __forceinline__ float rcp_f(float x) {
    float r; asm("v_rcp_f32 %0, %1" : "=v"(r) : "v"(x)); return r;
}
__device__ __forceinline__ float cos_rev(float x) {
    float fr, c;
    asm("v_fract_f32 %0, %1" : "=v"(fr) : "v"(x));
    asm("v_cos_f32 %0, %1" : "=v"(c) : "v"(fr));
    return c;
}
__device__ __forceinline__ float cos01(float x) {
    float c; asm("v_cos_f32 %0, %1" : "=v"(c) : "v"(x)); return c;
}
__device__ __forceinline__ u16 f2bf(float f) {
    u32 u = __float_as_uint(f);
    return (u16)((u + 0x7FFFu + ((u >> 16) & 1u)) >> 16);
}
__device__ __forceinline__ void gload16(const void* g, void* l) {
    __builtin_amdgcn_global_load_lds((const __attribute__((address_space(1))) void*)g,
                                     (__attribute__((address_space(3))) void*)l, 16, 0, 0);
}

// ---------------------------------------------------------------------------
// Fragment layouts (16B per lane-slot, bf16):
//   Lt_frag[(ot32*128 + ks)*64 + lane] : Linker[k][o] with
//       o = ot32*32 + (lane&31), k = ks*16 + (lane>>5)*8 + {0..7}
//   Vt_frag[((b*2+it32)*128 + ks)*64 + lane] : V[b][i][k] with
//       i = it32*32 + (lane&31), k = ks*16 + (lane>>5)*8 + {0..7}
// These are exactly the A/B fragments of v_mfma_f32_32x32x16_bf16.
// ---------------------------------------------------------------------------

// kT: Linker f32 [k][o] -> Lt_frag bf16
__global__ __launch_bounds__(256) void kT(const float* __restrict__ Lnk,
                                          u16* __restrict__ Lt) {
    __shared__ float lt[64][132];   // o-major transpose; pad 132 (16B-aligned rows)
    const int t = threadIdx.x;
    const int k0 = (blockIdx.x & 15) * 128;
    const int o0 = (blockIdx.x >> 4) * 64;
    {
        int kk = t >> 1, hf = t & 1;
        const float4* src = (const float4*)&Lnk[(size_t)(k0 + kk) * OSQ + o0 + hf * 32];
        #pragma unroll
        for (int q = 0; q < 8; ++q) {
            float4 v = src[q];
            int ob = hf * 32 + q * 4;
            lt[ob + 0][kk] = v.x;
            lt[ob + 1][kk] = v.y;
            lt[ob + 2][kk] = v.z;
            lt[ob + 3][kk] = v.w;
        }
    }
    __syncthreads();
    #pragma unroll
    for (int q = 0; q < 4; ++q) {
        int idx = q * 256 + t;
        int o = idx >> 4, s = idx & 15;
        float4 a = *(const float4*)&lt[o][s * 8];
        float4 b = *(const float4*)&lt[o][s * 8 + 4];
        uint4 pk;
        pk.x = (u32)f2bf(a.x) | ((u32)f2bf(a.y) << 16);
        pk.y = (u32)f2bf(a.z) | ((u32)f2bf(a.w) << 16);
        pk.z = (u32)f2bf(b.x) | ((u32)f2bf(b.y) << 16);
        pk.w = (u32)f2bf(b.z) | ((u32)f2bf(b.w) << 16);
        int og = o0 + o;
        size_t idx16 = ((size_t)(og >> 5) * 128 + ((k0 + s * 8) >> 4)) * 64
                     + (og & 31) + 32 * (s & 1);
        *(uint4*)&Lt[idx16 * 8] = pk;
    }
}

// ---------------------------------------------------------------------------
// kA: Z0 = seq@M^T (MFMA), LayerNorm, W on-the-fly (cos recurrence),
// T per-k (MFMA), V = T + Z0 -> Vt_frag. 4 barriers total.
// ---------------------------------------------------------------------------
__global__ __launch_bounds__(512, 2) void kA(const float* __restrict__ seq,
                                             const float* __restrict__ Mm,
                                             const float* __restrict__ P,
                                             const float* __restrict__ gamma,
                                             const float* __restrict__ beta,
                                             u16* __restrict__ Vt) {
    __shared__ __align__(16) u16 SEQb[64 * 64];   // bf16, swizzled by (row&7)
    __shared__ __align__(16) u16 Mb[64 * 64];     // bf16, swizzled by (o&7)
    __shared__ __align__(16) u16 SZb[64 * 64];    // Z bf16, swizzled by batch
    __shared__ float Z0l[64 * 68];                // pre-LN projection, f32
    __shared__ float Ta[8 * 2 * 64 * 11];         // T partials [kc][h][i][b pad11]

    const int t = threadIdx.x;
    const int l = t & 63;
    const int w = t >> 6;
    const int k0 = blockIdx.x * 8;
    const float kf0 = (float)k0;

    const int h = w >> 2;                 // j-half
    const int i0 = (w & 3) * 16;
    const int i_w = i0 + (l & 15);
    const int jc_w = h * 4 + (l >> 4);    // 8-j chunk 0..7

    float pr[40];
    {
        const float4* P4 = (const float4*)(P + ((size_t)i_w * 64 + jc_w * 8) * 5);
        #pragma unroll
        for (int q = 0; q < 10; ++q) {
            float4 v = P4[q];
            pr[q * 4 + 0] = v.x; pr[q * 4 + 1] = v.y; pr[q * 4 + 2] = v.z; pr[q * 4 + 3] = v.w;
        }
    }

    // stage seq, M as bf16 (swizzled)
    {
        int row = t >> 3, ch = t & 7;
        int b = row >> 3, kq = row & 7;
        const float* sp = &seq[((size_t)b * SS + k0 + kq) * DDIM + ch * 8];
        float4 a = *(const float4*)sp, bb4 = *(const float4*)(sp + 4);
        uint4 pk;
        pk.x = (u32)f2bf(a.x) | ((u32)f2bf(a.y) << 16);
        pk.y = (u32)f2bf(a.z) | ((u32)f2bf(a.w) << 16);
        pk.z = (u32)f2bf(bb4.x) | ((u32)f2bf(bb4.y) << 16);
        pk.w = (u32)f2bf(bb4.z) | ((u32)f2bf(bb4.w) << 16);
        *(uint4*)&SEQb[row * 64 + ((ch ^ (row & 7)) * 8)] = pk;

        const float* mp = &Mm[(size_t)row * DDIM + ch * 8];
        float4 c = *(const float4*)mp, d = *(const float4*)(mp + 4);
        uint4 pm;
        pm.x = (u32)f2bf(c.x) | ((u32)f2bf(c.y) << 16);
        pm.y = (u32)f2bf(c.z) | ((u32)f2bf(c.w) << 16);
        pm.z = (u32)f2bf(d.x) | ((u32)f2bf(d.y) << 16);
        pm.w = (u32)f2bf(d.z) | ((u32)f2bf(d.w) << 16);
        *(uint4*)&Mb[row * 64 + ((ch ^ (row & 7)) * 8)] = pm;
    }

    // cosine recurrence init (trans pipe, overlaps staging)
    float c0[40], c1[40], t2c[40];
    #pragma unroll
    for (int m = 0; m < 8; ++m) {
        #pragma unroll
        for (int g = 0; g < GG; ++g) {
            int idx = m * 5 + g;
            float pf = (float)((i_w * 64 + jc_w * 8 + m) * 5 + g + 2);
            float inv = rcp_f(pf);
            c0[idx] = cos_rev(kf0 * inv);
            c1[idx] = cos_rev((kf0 + 1.0f) * inv);
            float ct = cos01(inv);
            t2c[idx] = ct + ct;
        }
    }

    float gm[8], bt[8];
    {
        int oc = t & 7;
        float4 a = *(const float4*)&gamma[oc * 8], b = *(const float4*)&gamma[oc * 8 + 4];
        float4 c = *(const float4*)&beta[oc * 8],  d = *(const float4*)&beta[oc * 8 + 4];
        gm[0]=a.x; gm[1]=a.y; gm[2]=a.z; gm[3]=a.w; gm[4]=b.x; gm[5]=b.y; gm[6]=b.z; gm[7]=b.w;
        bt[0]=c.x; bt[1]=c.y; bt[2]=c.z; bt[3]=c.w; bt[4]=d.x; bt[5]=d.y; bt[6]=d.z; bt[7]=d.w;
    }
    __syncthreads();

    // phase 1: Z0 = seq @ M^T via mfma_32x32x16 (waves 0-3)
    if (w < 4) {
        const int qr = w & 1, qc = w >> 1;
        v16f acc = {0,0,0,0,0,0,0,0,0,0,0,0,0,0,0,0};
        const int rowA = qr * 32 + (l & 31);
        const int rowB = qc * 32 + (l & 31);
        #pragma unroll
        for (int ks = 0; ks < 4; ++ks) {
            int cA = (ks * 2 + (l >> 5)) ^ (rowA & 7);
            int cB = (ks * 2 + (l >> 5)) ^ (rowB & 7);
            s16x8 af = *(const s16x8*)&SEQb[rowA * 64 + cA * 8];
            s16x8 bf = *(const s16x8*)&Mb[rowB * 64 + cB * 8];
            acc = __builtin_amdgcn_mfma_f32_32x32x16_bf16(af, bf, acc, 0, 0, 0);
        }
        #pragma unroll
        for (int q = 0; q < 16; ++q) {
            int row = qr * 32 + (q & 3) + 8 * (q >> 2) + 4 * (l >> 5);
            int col = qc * 32 + (l & 31);
            Z0l[row * 68 + col] = acc[q];
        }
    }
    __syncthreads();

    // LayerNorm -> SZb bf16
    {
        const int rI = t >> 3, oc = t & 7;
        float z0v[8];
        float4 a = *(const float4*)&Z0l[rI * 68 + oc * 8];
        float4 b = *(const float4*)&Z0l[rI * 68 + oc * 8 + 4];
        z0v[0]=a.x; z0v[1]=a.y; z0v[2]=a.z; z0v[3]=a.w; z0v[4]=b.x; z0v[5]=b.y; z0v[6]=b.z; z0v[7]=b.w;
        float s1 = ((z0v[0]+z0v[1])+(z0v[2]+z0v[3])) + ((z0v[4]+z0v[5])+(z0v[6]+z0v[7]));
        s1 += __shfl_xor(s1, 1); s1 += __shfl_xor(s1, 2); s1 += __shfl_xor(s1, 4);
        float mu = s1 * 0.015625f;
        float sq = 0.f;
        #pragma unroll
        for (int m = 0; m < 8; ++m) { float dv = z0v[m] - mu; sq = fmaf(dv, dv, sq); }
        sq += __shfl_xor(sq, 1); sq += __shfl_xor(sq, 2); sq += __shfl_xor(sq, 4);
        float rstd = rsqrtf(sq * 0.015625f + 1e-5f);
        u16 zb[8];
        #pragma unroll
        for (int m = 0; m < 8; ++m)
            zb[m] = f2bf(fmaf((z0v[m] - mu) * rstd, gm[m], bt[m]));
        uint4 pk;
        pk.x = (u32)zb[0] | ((u32)zb[1] << 16);
        pk.y = (u32)zb[2] | ((u32)zb[3] << 16);
        pk.z = (u32)zb[4] | ((u32)zb[5] << 16);
        pk.w = (u32)zb[6] | ((u32)zb[7] << 16);
        int slot = oc ^ ((rI >> 3) & 7);
        *(uint4*)&SZb[rI * 64 + slot * 8] = pk;
    }
    __syncthreads();

    // phase 2: all 8 kc, NO barriers (waves write disjoint Ta slices)
    const int bcl = l & 7;
    #pragma unroll
    for (int kc = 0; kc < 8; ++kc) {
        if (kc >= 2) {
            #pragma unroll
            for (int x = 0; x < 40; ++x) {
                float cn = fmaf(t2c[x], c1[x], -c0[x]);
                c0[x] = c1[x]; c1[x] = cn;
            }
        }
        s16x8 bw;
        #pragma unroll
        for (int j = 0; j < 8; ++j) {
            float a = 0.f;
            #pragma unroll
            for (int g = 0; g < GG; ++g) {
                float ph = (kc == 0) ? c0[j * 5 + g] : c1[j * 5 + g];
                a = fmaf(pr[j * 5 + g], ph, a);
            }
            bw[j] = (short)f2bf(a);
        }
        int arow = bcl * 8 + kc;
        int slot = (h * 4 + (l >> 4)) ^ bcl;
        s16x8 az = *(const s16x8*)&SZb[arow * 64 + slot * 8];
        v4f zc = {0.f, 0.f, 0.f, 0.f};
        v4f d = __builtin_amdgcn_mfma_f32_16x16x32_bf16(az, bw, zc, 0, 0, 0);
        if (l < 32) {
            int ii = i0 + (l & 15);
            int bb = (l >> 4) * 4;
            #pragma unroll
            for (int r = 0; r < 4; ++r)
                Ta[((kc * 2 + h) * 64 + ii) * 11 + bb + r] = d[r];
        }
    }
    __syncthreads();

    // assembly: thread (w=b, l=i): V = T(h0)+T(h1)+Z0, write Vt fragment
    {
        float vk[8];
        #pragma unroll
        for (int kc = 0; kc < 8; ++kc)
            vk[kc] = Ta[((kc * 2 + 0) * 64 + l) * 11 + w]
                   + Ta[((kc * 2 + 1) * 64 + l) * 11 + w]
                   + Z0l[(w * 8 + kc) * 68 + l];
        uint4 pk;
        pk.x = (u32)f2bf(vk[0]) | ((u32)f2bf(vk[1]) << 16);
        pk.y = (u32)f2bf(vk[2]) | ((u32)f2bf(vk[3]) << 16);
        pk.z = (u32)f2bf(vk[4]) | ((u32)f2bf(vk[5]) << 16);
        pk.w = (u32)f2bf(vk[6]) | ((u32)f2bf(vk[7]) << 16);
        const int ks = k0 >> 4;
        const int hi = (k0 >> 3) & 1;
        size_t idx16 = ((size_t)(w * 2 + (l >> 5)) * 128 + ks) * 64 + (l & 31) + 32 * hi;
        *(uint4*)&Vt[idx16 * 8] = pk;
    }
}

// ---------------------------------------------------------------------------
// kB: part[kw][b][o][i], 256 blocks x 4 waves; each wave: one 32x32 tile over
// K=512, double-buffered global_load_lds (counted vmcnt), ZERO barriers.
// ---------------------------------------------------------------------------
__global__ __launch_bounds__(256, 2) void kB(const u16* __restrict__ Lt,
                                             const u16* __restrict__ Vt,
                                             float* __restrict__ part) {
    __shared__ __align__(16) u16 LB[4][2][2][2048];  // [wave][buf][A/B][4KB]
    const int t = threadIdx.x;
    const int l = t & 63, w = t >> 6;
    const int bid = blockIdx.x;
    const int kw = bid & 3, ot = (bid >> 2) & 7, b = bid >> 5;
    const int so = w & 1, si = w >> 1;

    const u16* aG = Lt + (((size_t)(ot * 2 + so) * 128 + kw * 32) * 64 + l) * 8;
    const u16* bG = Vt + (((size_t)(b * 2 + si) * 128 + kw * 32) * 64 + l) * 8;

    v16f acc0 = {0,0,0,0,0,0,0,0,0,0,0,0,0,0,0,0};
    v16f acc1 = acc0;

#define STAGE(c, buf)                                                          \
    {                                                                          \
        _Pragma("unroll")                                                      \
        for (int ksl = 0; ksl < 4; ++ksl) {                                    \
            gload16(aG + ((c) * 4 + ksl) * 512, &LB[w][buf][0][ksl * 512]);    \
            gload16(bG + ((c) * 4 + ksl) * 512, &LB[w][buf][1][ksl * 512]);    \
        }                                                                      \
    }

    STAGE(0, 0);
    STAGE(1, 1);
    #pragma unroll
    for (int c = 0; c < 8; ++c) {
        if (c < 7) { asm volatile("s_waitcnt vmcnt(8)" ::: "memory"); }
        else       { asm volatile("s_waitcnt vmcnt(0)" ::: "memory"); }
        __builtin_amdgcn_sched_barrier(0);
        const int buf = c & 1;
        #pragma unroll
        for (int ksl = 0; ksl < 4; ++ksl) {
            s16x8 A = *(const s16x8*)&LB[w][buf][0][ksl * 512 + l * 8];
            s16x8 B = *(const s16x8*)&LB[w][buf][1][ksl * 512 + l * 8];
            if (ksl & 1) acc1 = __builtin_amdgcn_mfma_f32_32x32x16_bf16(A, B, acc1, 0, 0, 0);
            else         acc0 = __builtin_amdgcn_mfma_f32_32x32x16_bf16(A, B, acc0, 0, 0, 0);
        }
        asm volatile("s_waitcnt lgkmcnt(0)" ::: "memory");
        __builtin_amdgcn_sched_barrier(0);
        if (c + 2 < 8) STAGE(c + 2, buf);
    }
#undef STAGE

    float* dst = part + ((size_t)(kw * 8 + b) * OSQ + ot * 64 + so * 32) * 64
               + si * 32 + (l & 31);
    #pragma unroll
    for (int r = 0; r < 16; ++r) {
        int orow = (r & 3) + 8 * (r >> 2) + 4 * (l >> 5);
        dst[(size_t)orow * 64] = acc0[r] + acc1[r];
    }
}

// kC: out = sum of 4 K-split partials
__global__ __launch_bounds__(256) void kC(const float* __restrict__ part,
                                          float* __restrict__ out) {
    const int x = blockIdx.x * 256 + threadIdx.x;   // float4 index, 65536 total
    const float4* p4 = (const float4*)part;
    float4 s = p4[x];
    #pragma unroll
    for (int p = 1; p < 4; ++p) {
        float4 a = p4[x + p * 65536];
        s.x += a.x; s.y += a.y; s.z += a.z; s.w += a.w;
    }
    ((float4*)out)[x] = s;
}

extern "C" void kernel_launch(void* const* d_in, const int* in_sizes, int n_in,
                              void* d_out, int out_size, void* d_ws, size_t ws_size,
                              hipStream_t stream) {
    const float* seq   = (const float*)d_in[0];
    const float* Mm    = (const float*)d_in[1];
    const float* P     = (const float*)d_in[2];
    const float* Lnk   = (const float*)d_in[3];
    const float* gamma = (const float*)d_in[4];
    const float* beta  = (const float*)d_in[5];

    u16* Lt    = (u16*)d_ws;                              // 2 MB
    u16* Vt    = (u16*)((char*)d_ws + (2u << 20));        // 2 MB
    float* prt = (float*)((char*)d_ws + (4u << 20));      // 4 MB

    kT<<<128, 256, 0, stream>>>(Lnk, Lt);
    kA<<<256, 512, 0, stream>>>(seq, Mm, P, gamma, beta, Vt);
    kB<<<256, 256, 0, stream>>>(Lt, Vt, prt);
    kC<<<256, 256, 0, stream>>>(prt, (float*)d_out);
}

// Round 4
// 21.428 us; speedup vs baseline: 2.2644x; 1.2868x over previous
//
#include <hip/hip_runtime.h>
#include <math.h>

#define SS 2048
#define OSQ 512
#define GG 5

typedef unsigned short u16;
typedef unsigned int u32;
typedef __attribute__((ext_vector_type(8))) short s16x8;
typedef __attribute__((ext_vector_type(4))) float v4f;
typedef __attribute__((ext_vector_type(16))) float v16f;

__device__ __forceinline__ float rcp_f(float x) {
    float r; asm("v_rcp_f32 %0, %1" : "=v"(r) : "v"(x)); return r;
}
__device__ __forceinline__ float cos_rev(float x) {
    float fr, c;
    asm("v_fract_f32 %0, %1" : "=v"(fr) : "v"(x));
    asm("v_cos_f32 %0, %1" : "=v"(c) : "v"(fr));
    return c;
}
__device__ __forceinline__ float cos01(float x) {
    float c; asm("v_cos_f32 %0, %1" : "=v"(c) : "v"(x)); return c;
}
__device__ __forceinline__ u16 f2bf(float f) {
    u32 u = __float_as_uint(f);
    return (u16)((u + 0x7FFFu + ((u >> 16) & 1u)) >> 16);
}
__device__ __forceinline__ float bf2f(u16 h) {
    return __uint_as_float((u32)h << 16);
}
__device__ __forceinline__ void gload16(const void* g, void* l) {
    __builtin_amdgcn_global_load_lds((const __attribute__((address_space(1))) void*)g,
                                     (__attribute__((address_space(3))) void*)l, 16, 0, 0);
}

// ---------------------------------------------------------------------------
// Fragment layouts (16B per lane-slot, bf16):
//   Lt_frag[(o32blk*128 + ks)*64 + slot] : Linker[k][o],
//       o = o32blk*32 + (slot&31), k = ks*16 + (slot>>5)*8 + {0..7}
//   Vt_frag[((b*2+i32blk)*128 + ks)*64 + slot] : V[b][i][k], same slot rule.
// Exactly the A/B operand fragments of v_mfma_f32_32x32x16_bf16.
// ---------------------------------------------------------------------------

// kF: blocks 0..127   -> Linker transpose/pack into Lt fragments (LDS-free)
//     blocks 128..383 -> fused Z0 = seq@M^T (MFMA), LayerNorm, W on-the-fly
//                        (cos recurrence), T (MFMA), V = T+Z0 -> Vt fragments.
__global__ __launch_bounds__(512, 1) void kF(const float* __restrict__ seq,
                                             const float* __restrict__ Mm,
                                             const float* __restrict__ P,
                                             const float* __restrict__ gamma,
                                             const float* __restrict__ beta,
                                             const float* __restrict__ Lnk,
                                             u16* __restrict__ Lt,
                                             u16* __restrict__ Vt) {
    __shared__ __align__(16) u16 SEQb[64 * 64];   // bf16, swizzled by (row&7)
    __shared__ __align__(16) u16 Mb[64 * 64];     // bf16, swizzled by (o&7)
    __shared__ __align__(16) u16 SZb[64 * 64];    // Z bf16, swizzled by batch
    __shared__ float Z0l[64 * 68];                // pre-LN projection, f32
    __shared__ u32 Ta32[8 * 2 * 64 * 5];          // T partials bf16 [kc][h][i][10 u16]

    const int t = threadIdx.x;

    if (blockIdx.x < 128) {
        // ---- Lt emission: coalesced row reads (lane = o), pack in regs ----
        const int tb = blockIdx.x;
        const int k0t = (tb & 15) * 128;
        const int o0 = (tb >> 4) * 64;
        const int og = o0 + (t & 63);
        const int sp2 = (t >> 6) * 2;
        #pragma unroll
        for (int ss2 = 0; ss2 < 2; ++ss2) {
            const int s = sp2 + ss2;
            float v[8];
            #pragma unroll
            for (int j = 0; j < 8; ++j)
                v[j] = Lnk[(size_t)(k0t + s * 8 + j) * OSQ + og];
            uint4 pk;
            pk.x = (u32)f2bf(v[0]) | ((u32)f2bf(v[1]) << 16);
            pk.y = (u32)f2bf(v[2]) | ((u32)f2bf(v[3]) << 16);
            pk.z = (u32)f2bf(v[4]) | ((u32)f2bf(v[5]) << 16);
            pk.w = (u32)f2bf(v[6]) | ((u32)f2bf(v[7]) << 16);
            size_t idx16 = ((size_t)(og >> 5) * 128 + ((k0t + s * 8) >> 4)) * 64
                         + (og & 31) + 32 * (s & 1);
            *(uint4*)&Lt[idx16 * 8] = pk;
        }
        return;
    }

    const int bidA = blockIdx.x - 128;
    const int l = t & 63;
    const int w = t >> 6;
    const int k0 = bidA * 8;
    const float kf0 = (float)k0;

    const int h = w >> 2;                 // j-half
    const int i0 = (w & 3) * 16;
    const int i_w = i0 + (l & 15);
    const int jc_w = h * 4 + (l >> 4);    // 8-j chunk 0..7

    float pr[40];
    {
        const float4* P4 = (const float4*)(P + ((size_t)i_w * 64 + jc_w * 8) * 5);
        #pragma unroll
        for (int q = 0; q < 10; ++q) {
            float4 v = P4[q];
            pr[q * 4 + 0] = v.x; pr[q * 4 + 1] = v.y; pr[q * 4 + 2] = v.z; pr[q * 4 + 3] = v.w;
        }
    }

    // stage seq, M as bf16 (swizzled)
    {
        int row = t >> 3, ch = t & 7;
        int b = row >> 3, kq = row & 7;
        const float* sp = &seq[((size_t)b * SS + k0 + kq) * 64 + ch * 8];
        float4 a = *(const float4*)sp, bb4 = *(const float4*)(sp + 4);
        uint4 pk;
        pk.x = (u32)f2bf(a.x) | ((u32)f2bf(a.y) << 16);
        pk.y = (u32)f2bf(a.z) | ((u32)f2bf(a.w) << 16);
        pk.z = (u32)f2bf(bb4.x) | ((u32)f2bf(bb4.y) << 16);
        pk.w = (u32)f2bf(bb4.z) | ((u32)f2bf(bb4.w) << 16);
        *(uint4*)&SEQb[row * 64 + ((ch ^ (row & 7)) * 8)] = pk;

        const float* mp = &Mm[(size_t)row * 64 + ch * 8];
        float4 c = *(const float4*)mp, d = *(const float4*)(mp + 4);
        uint4 pm;
        pm.x = (u32)f2bf(c.x) | ((u32)f2bf(c.y) << 16);
        pm.y = (u32)f2bf(c.z) | ((u32)f2bf(c.w) << 16);
        pm.z = (u32)f2bf(d.x) | ((u32)f2bf(d.y) << 16);
        pm.w = (u32)f2bf(d.z) | ((u32)f2bf(d.w) << 16);
        *(uint4*)&Mb[row * 64 + ((ch ^ (row & 7)) * 8)] = pm;
    }

    // cosine recurrence init (trans pipe, overlaps staging)
    float c0[40], c1[40], t2c[40];
    #pragma unroll
    for (int m = 0; m < 8; ++m) {
        #pragma unroll
        for (int g = 0; g < GG; ++g) {
            int idx = m * 5 + g;
            float pf = (float)((i_w * 64 + jc_w * 8 + m) * 5 + g + 2);
            float inv = rcp_f(pf);
            c0[idx] = cos_rev(kf0 * inv);
            c1[idx] = cos_rev((kf0 + 1.0f) * inv);
            float ct = cos01(inv);
            t2c[idx] = ct + ct;
        }
    }

    float gm[8], bt[8];
    {
        int oc = t & 7;
        float4 a = *(const float4*)&gamma[oc * 8], b = *(const float4*)&gamma[oc * 8 + 4];
        float4 c = *(const float4*)&beta[oc * 8],  d = *(const float4*)&beta[oc * 8 + 4];
        gm[0]=a.x; gm[1]=a.y; gm[2]=a.z; gm[3]=a.w; gm[4]=b.x; gm[5]=b.y; gm[6]=b.z; gm[7]=b.w;
        bt[0]=c.x; bt[1]=c.y; bt[2]=c.z; bt[3]=c.w; bt[4]=d.x; bt[5]=d.y; bt[6]=d.z; bt[7]=d.w;
    }
    __syncthreads();

    // phase 1: Z0 = seq @ M^T via mfma_32x32x16 (waves 0-3)
    if (w < 4) {
        const int qr = w & 1, qc = w >> 1;
        v16f acc = {0,0,0,0,0,0,0,0,0,0,0,0,0,0,0,0};
        const int rowA = qr * 32 + (l & 31);
        const int rowB = qc * 32 + (l & 31);
        #pragma unroll
        for (int ks = 0; ks < 4; ++ks) {
            int cA = (ks * 2 + (l >> 5)) ^ (rowA & 7);
            int cB = (ks * 2 + (l >> 5)) ^ (rowB & 7);
            s16x8 af = *(const s16x8*)&SEQb[rowA * 64 + cA * 8];
            s16x8 bf = *(const s16x8*)&Mb[rowB * 64 + cB * 8];
            acc = __builtin_amdgcn_mfma_f32_32x32x16_bf16(af, bf, acc, 0, 0, 0);
        }
        #pragma unroll
        for (int q = 0; q < 16; ++q) {
            int row = qr * 32 + (q & 3) + 8 * (q >> 2) + 4 * (l >> 5);
            int col = qc * 32 + (l & 31);
            Z0l[row * 68 + col] = acc[q];
        }
    }
    __syncthreads();

    // LayerNorm -> SZb bf16
    {
        const int rI = t >> 3, oc = t & 7;
        float z0v[8];
        float4 a = *(const float4*)&Z0l[rI * 68 + oc * 8];
        float4 b = *(const float4*)&Z0l[rI * 68 + oc * 8 + 4];
        z0v[0]=a.x; z0v[1]=a.y; z0v[2]=a.z; z0v[3]=a.w; z0v[4]=b.x; z0v[5]=b.y; z0v[6]=b.z; z0v[7]=b.w;
        float s1 = ((z0v[0]+z0v[1])+(z0v[2]+z0v[3])) + ((z0v[4]+z0v[5])+(z0v[6]+z0v[7]));
        s1 += __shfl_xor(s1, 1); s1 += __shfl_xor(s1, 2); s1 += __shfl_xor(s1, 4);
        float mu = s1 * 0.015625f;
        float sq = 0.f;
        #pragma unroll
        for (int m = 0; m < 8; ++m) { float dv = z0v[m] - mu; sq = fmaf(dv, dv, sq); }
        sq += __shfl_xor(sq, 1); sq += __shfl_xor(sq, 2); sq += __shfl_xor(sq, 4);
        float rstd = rsqrtf(sq * 0.015625f + 1e-5f);
        u16 zb[8];
        #pragma unroll
        for (int m = 0; m < 8; ++m)
            zb[m] = f2bf(fmaf((z0v[m] - mu) * rstd, gm[m], bt[m]));
        uint4 pk;
        pk.x = (u32)zb[0] | ((u32)zb[1] << 16);
        pk.y = (u32)zb[2] | ((u32)zb[3] << 16);
        pk.z = (u32)zb[4] | ((u32)zb[5] << 16);
        pk.w = (u32)zb[6] | ((u32)zb[7] << 16);
        int slot = oc ^ ((rI >> 3) & 7);
        *(uint4*)&SZb[rI * 64 + slot * 8] = pk;
    }
    __syncthreads();

    // phase 2: all 8 kc, no barriers (waves write disjoint Ta slices)
    const int bcl = l & 7;
    #pragma unroll
    for (int kc = 0; kc < 8; ++kc) {
        if (kc >= 2) {
            #pragma unroll
            for (int x = 0; x < 40; ++x) {
                float cn = fmaf(t2c[x], c1[x], -c0[x]);
                c0[x] = c1[x]; c1[x] = cn;
            }
        }
        s16x8 bw;
        #pragma unroll
        for (int j = 0; j < 8; ++j) {
            float a = 0.f;
            #pragma unroll
            for (int g = 0; g < GG; ++g) {
                float ph = (kc == 0) ? c0[j * 5 + g] : c1[j * 5 + g];
                a = fmaf(pr[j * 5 + g], ph, a);
            }
            bw[j] = (short)f2bf(a);
        }
        int arow = bcl * 8 + kc;
        int slot = (h * 4 + (l >> 4)) ^ bcl;
        s16x8 az = *(const s16x8*)&SZb[arow * 64 + slot * 8];
        v4f zc = {0.f, 0.f, 0.f, 0.f};
        v4f d = __builtin_amdgcn_mfma_f32_16x16x32_bf16(az, bw, zc, 0, 0, 0);
        if (l < 32) {
            int ii = i0 + (l & 15);
            int bb2 = (l >> 4) * 2;
            u32 base = (u32)((kc * 2 + h) * 64 + ii) * 5 + bb2;
            Ta32[base]     = (u32)f2bf(d[0]) | ((u32)f2bf(d[1]) << 16);
            Ta32[base + 1] = (u32)f2bf(d[2]) | ((u32)f2bf(d[3]) << 16);
        }
    }
    __syncthreads();

    // assembly: thread (w=b, l=i): V = T(h0)+T(h1)+Z0, write Vt fragment
    {
        const u16* TaR = (const u16*)Ta32;
        float vk[8];
        #pragma unroll
        for (int kc = 0; kc < 8; ++kc)
            vk[kc] = bf2f(TaR[((kc * 2 + 0) * 64 + l) * 10 + w])
                   + bf2f(TaR[((kc * 2 + 1) * 64 + l) * 10 + w])
                   + Z0l[(w * 8 + kc) * 68 + l];
        uint4 pk;
        pk.x = (u32)f2bf(vk[0]) | ((u32)f2bf(vk[1]) << 16);
        pk.y = (u32)f2bf(vk[2]) | ((u32)f2bf(vk[3]) << 16);
        pk.z = (u32)f2bf(vk[4]) | ((u32)f2bf(vk[5]) << 16);
        pk.w = (u32)f2bf(vk[6]) | ((u32)f2bf(vk[7]) << 16);
        const int ks = k0 >> 4;
        const int hi = (k0 >> 3) & 1;
        size_t idx16 = ((size_t)(w * 2 + (l >> 5)) * 128 + ks) * 64 + (l & 31) + 32 * hi;
        *(uint4*)&Vt[idx16 * 8] = pk;
    }
}

// ---------------------------------------------------------------------------
// kB2: out[b][o][i] direct. Grid 256 = (b=8, ot=16, it=2); block = 32o x 32i
// over full K=2048; 4 waves split K (512 each), zero barriers in main loop;
// 2-barrier LDS reduce of the 4 wave-partials, then coalesced store.
// ---------------------------------------------------------------------------
__global__ __launch_bounds__(256, 2) void kB2(const u16* __restrict__ Lt,
                                              const u16* __restrict__ Vt,
                                              float* __restrict__ out) {
    __shared__ __align__(16) u16 LB[4][2][2][2048];  // [wave][buf][A/B] 4KB each
    const int t = threadIdx.x;
    const int l = t & 63, w = t >> 6;
    const int bid = blockIdx.x;
    const int it = bid & 1, ot = (bid >> 1) & 15, b = bid >> 5;

    const u16* aG = Lt + (((size_t)ot * 128 + w * 32) * 64 + l) * 8;
    const u16* bG = Vt + (((size_t)(b * 2 + it) * 128 + w * 32) * 64 + l) * 8;

    v16f acc0 = {0,0,0,0,0,0,0,0,0,0,0,0,0,0,0,0};
    v16f acc1 = acc0;

#define STAGE(c, buf)                                                          \
    {                                                                          \
        _Pragma("unroll")                                                      \
        for (int ksl = 0; ksl < 4; ++ksl) {                                    \
            gload16(aG + ((c) * 4 + ksl) * 512, &LB[w][buf][0][ksl * 512]);    \
            gload16(bG + ((c) * 4 + ksl) * 512, &LB[w][buf][1][ksl * 512]);    \
        }                                                                      \
    }

    STAGE(0, 0);
    STAGE(1, 1);
    #pragma unroll
    for (int c = 0; c < 8; ++c) {
        if (c < 7) { asm volatile("s_waitcnt vmcnt(8)" ::: "memory"); }
        else       { asm volatile("s_waitcnt vmcnt(0)" ::: "memory"); }
        __builtin_amdgcn_sched_barrier(0);
        const int buf = c & 1;
        #pragma unroll
        for (int ksl = 0; ksl < 4; ++ksl) {
            s16x8 A = *(const s16x8*)&LB[w][buf][0][ksl * 512 + l * 8];
            s16x8 B = *(const s16x8*)&LB[w][buf][1][ksl * 512 + l * 8];
            if (ksl & 1) acc1 = __builtin_amdgcn_mfma_f32_32x32x16_bf16(A, B, acc1, 0, 0, 0);
            else         acc0 = __builtin_amdgcn_mfma_f32_32x32x16_bf16(A, B, acc0, 0, 0, 0);
        }
        asm volatile("s_waitcnt lgkmcnt(0)" ::: "memory");
        __builtin_amdgcn_sched_barrier(0);
        if (c + 2 < 8) STAGE(c + 2, buf);
    }
#undef STAGE

    // cross-wave K reduction in LDS (reuse LB), stride 17 = conflict-free
    __syncthreads();
    float* red = (float*)LB;
    {
        const int base = (w * 64 + l) * 17;
        #pragma unroll
        for (int r = 0; r < 16; ++r) red[base + r] = acc0[r] + acc1[r];
    }
    __syncthreads();
    {
        const int icol = t & 31;
        const int ob = (t >> 5) * 4;
        #pragma unroll
        for (int q = 0; q < 4; ++q) {
            const int orow = ob + q;
            const int hi = (orow >> 2) & 1;
            const int r = (orow & 3) | ((orow >> 3) << 2);
            const int lp = icol + 32 * hi;
            float s = red[(0 * 64 + lp) * 17 + r] + red[(1 * 64 + lp) * 17 + r]
                    + red[(2 * 64 + lp) * 17 + r] + red[(3 * 64 + lp) * 17 + r];
            out[((size_t)b * OSQ + ot * 32 + orow) * 64 + it * 32 + icol] = s;
        }
    }
}

extern "C" void kernel_launch(void* const* d_in, const int* in_sizes, int n_in,
                              void* d_out, int out_size, void* d_ws, size_t ws_size,
                              hipStream_t stream) {
    const float* seq   = (const float*)d_in[0];
    const float* Mm    = (const float*)d_in[1];
    const float* P     = (const float*)d_in[2];
    const float* Lnk   = (const float*)d_in[3];
    const float* gamma = (const float*)d_in[4];
    const float* beta  = (const float*)d_in[5];

    u16* Lt = (u16*)d_ws;                          // 512*2048 bf16 = 2 MB
    u16* Vt = (u16*)((char*)d_ws + (2u << 20));    // 8*64*2048 bf16 = 2 MB

    kF<<<384, 512, 0, stream>>>(seq, Mm, P, gamma, beta, Lnk, Lt, Vt);
    kB2<<<256, 256, 0, stream>>>(Lt, Vt, (float*)d_out);
}